// Round 9
// baseline (183.164 us; speedup 1.0000x reference)
//
#include <hip/hip_runtime.h>

// AugmentedNeuralODE, round 9: R8 + within-eval latency restructure.
// Occupancy is structurally capped at 1 wave/SIMD (1024 waves = B/16; any
// split needs LDS exchange = the R3-R7 bottleneck). So: maximize in-stream
// ILP. Changes vs R8 (math-preserving):
//   1. Phase-separated feval: all 16 L1 tanh-pairs (16 indep chains) ->
//      32 MFMAs kk-major (8 indep acc chains, pipelined) -> epilogue
//      (tile 0's acc is ready 8 MFMAs before the burst ends -> drain hidden).
//   2. Epilogue vs-accumulation split into 4 independent chains (was one
//      32-deep serial pk_fma chain = ~128 cyc exposed latency).
//   3. exp-based tanh kept (2 full + 4 trans/pair is issue-optimal);
//      ss-loop kept at unroll 1 (body ~24KB, near 32KB L1I).
// W2 A-frags (128) + b2 acc-init (32) pinned in AGPRs; W1/W3/state in arch
// VGPRs; no LDS, no barriers, no spills.

#define HID 128
#define TT  8
#define F(a,b) ((float)((double)(a)/(double)(b)))
#define K2C 2.8853900817779268f   // 2*log2(e), folded into W1/b1/W2/b2

typedef __attribute__((ext_vector_type(8))) short bf16x8;
typedef __attribute__((ext_vector_type(4))) float f32x4;
typedef __attribute__((ext_vector_type(2))) float f32x2;

union Frag { bf16x8 v; unsigned short u[8]; unsigned int d[4]; };

__device__ __forceinline__ f32x2 bc(float s) { return f32x2{s, s}; }
__device__ __forceinline__ f32x2 pk_fma(f32x2 a, f32x2 b, f32x2 c) {
#if __has_builtin(__builtin_elementwise_fma)
  return __builtin_elementwise_fma(a, b, c);
#else
  return a * b + c;
#endif
}
__device__ __forceinline__ float exp2_fast(float x) {
#if __has_builtin(__builtin_amdgcn_exp2f)
  return __builtin_amdgcn_exp2f(x);
#else
  return __builtin_exp2f(x);
#endif
}
__device__ __forceinline__ unsigned short f2bf(float f) {
  unsigned u = __builtin_bit_cast(unsigned, f);
  u += 0x7FFFu + ((u >> 16) & 1u);          // RNE
  return (unsigned short)(u >> 16);
}
__device__ __forceinline__ unsigned pack2bf(float a, float b) {
  unsigned ua = __builtin_bit_cast(unsigned, a);
  unsigned ub = __builtin_bit_cast(unsigned, b);
  ua += 0x7FFFu + ((ua >> 16) & 1u);
  ub += 0x7FFFu + ((ub >> 16) & 1u);
  return __builtin_amdgcn_perm(ub, ua, 0x07060302u);
}
// u pre-scaled by 2*log2(e): tanh(x) = 1 - 2/(exp2(u)+1)
__device__ __forceinline__ f32x2 tanh_pre(f32x2 u) {
  f32x2 e;
  e.x = exp2_fast(u.x);
  e.y = exp2_fast(u.y);
  f32x2 d = e + bc(1.0f);
  f32x2 r;
  r.x = __builtin_amdgcn_rcpf(d.x);
  r.y = __builtin_amdgcn_rcpf(d.y);
  return pk_fma(bc(-2.0f), r, bc(1.0f));
}

__global__ __launch_bounds__(64, 1) void node_kernel(
    const float* __restrict__ r0, const float* __restrict__ tarr,
    const float* __restrict__ W1, const float* __restrict__ b1,
    const float* __restrict__ W2, const float* __restrict__ b2,
    const float* __restrict__ W3, const float* __restrict__ b3,
    float* __restrict__ out)
{
  const int lane = (int)(threadIdx.x & 63u);
  const int quad = lane >> 4;          // 0..3
  const int m16  = lane & 15;          // my sample (column)
  const int s    = (int)blockIdx.x * 16 + m16;

  // ---- one-time preloads, all K2-folded ----
  // W1 for my 32 units k = kk*32 + quad*8 + j (16 pairs) -- arch VGPRs (128)
  f32x2 w1x[16], w1y[16], w1t[16], bb1[16];
  #pragma unroll
  for (int kk = 0; kk < 4; ++kk)
    #pragma unroll
    for (int p = 0; p < 4; ++p) {
      int i = kk * 32 + quad * 8 + 2 * p;
      int idx = kk * 4 + p;
      w1x[idx] = f32x2{W1[0 * HID + i], W1[0 * HID + i + 1]} * bc(K2C);
      w1y[idx] = f32x2{W1[1 * HID + i], W1[1 * HID + i + 1]} * bc(K2C);
      w1t[idx] = f32x2{W1[4 * HID + i], W1[4 * HID + i + 1]} * bc(K2C);
      bb1[idx] = f32x2{b1[i], b1[i + 1]} * bc(K2C);
    }
  // W2 A-frags for ALL 8 out-tiles -> pinned into AGPRs (128 regs)
  Frag W2f[8][4];
  #pragma unroll
  for (int t = 0; t < 8; ++t) {
    int o = t * 16 + m16;
    #pragma unroll
    for (int kk = 0; kk < 4; ++kk) {
      #pragma unroll
      for (int j = 0; j < 8; ++j)
        W2f[t][kk].u[j] = f2bf(W2[(kk * 32 + quad * 8 + j) * HID + o] * K2C);
      asm volatile("" : "+a"(W2f[t][kk].v));   // park in AGPR (MFMA A-src)
    }
  }
  // acc-init = b2*K2 -> pinned into AGPRs (32 regs, MFMA C-src)
  f32x4 b2i[8];
  f32x2 w3v[8][4];                      // W3 stays in arch (64 regs)
  #pragma unroll
  for (int t = 0; t < 8; ++t) {
    #pragma unroll
    for (int rr = 0; rr < 4; ++rr) {
      int o = t * 16 + quad * 4 + rr;
      b2i[t][rr] = b2[o] * K2C;
      w3v[t][rr] = f32x2{W3[o * 2 + 0], W3[o * 2 + 1]};
    }
    asm volatile("" : "+a"(b2i[t]));
  }
  const f32x2 b3v = f32x2{b3[0], b3[1]};

  f32x2 S = f32x2{r0[2 * s + 0], r0[2 * s + 1]};
  if (lane < 16) *(float2*)&out[(s * TT + 0) * 2] = make_float2(S.x, S.y);

  auto feval = [&](float tt, f32x2 st) -> f32x2 {
    const f32x2 sx = bc(st.x), sy = bc(st.y), tv = bc(tt);
    // ---- phase 1: all 32 L1 units (16 independent tanh chains) ----
    unsigned hd[16];
    #pragma unroll
    for (int idx = 0; idx < 16; ++idx) {
      f32x2 a = pk_fma(sx, w1x[idx], bb1[idx]);
      a = pk_fma(sy, w1y[idx], a);
      a = pk_fma(tv, w1t[idx], a);
      f32x2 h = tanh_pre(a);
      hd[idx] = pack2bf(h.x, h.y);
    }
    // ---- phase 2: 32 MFMAs kk-major (8 independent acc chains) ----
    f32x4 acc[8];
    #pragma unroll
    for (int kk = 0; kk < 4; ++kk) {
      Frag bv;
      bv.d[0] = hd[kk * 4 + 0]; bv.d[1] = hd[kk * 4 + 1];
      bv.d[2] = hd[kk * 4 + 2]; bv.d[3] = hd[kk * 4 + 3];
      if (kk == 0) {
        #pragma unroll
        for (int t = 0; t < 8; ++t)
          acc[t] = __builtin_amdgcn_mfma_f32_16x16x32_bf16(
              W2f[t][0].v, bv.v, b2i[t], 0, 0, 0);
      } else {
        #pragma unroll
        for (int t = 0; t < 8; ++t)
          acc[t] = __builtin_amdgcn_mfma_f32_16x16x32_bf16(
              W2f[t][kk].v, bv.v, acc[t], 0, 0, 0);
      }
    }
    // ---- phase 3: epilogue; tile 0's acc ready 8 MFMAs before burst end.
    // 4 independent vs chains (was one 32-deep serial pk_fma chain).
    f32x2 vsa[4] = {bc(0.f), bc(0.f), bc(0.f), bc(0.f)};
    #pragma unroll
    for (int t = 0; t < 8; ++t)
      #pragma unroll
      for (int p = 0; p < 2; ++p) {
        f32x2 av = f32x2{acc[t][2 * p], acc[t][2 * p + 1]};
        f32x2 h2 = tanh_pre(av);
        vsa[t & 3] = pk_fma(bc(h2.x), w3v[t][2 * p + 0], vsa[t & 3]);
        vsa[t & 3] = pk_fma(bc(h2.y), w3v[t][2 * p + 1], vsa[t & 3]);
      }
    f32x2 vs = (vsa[0] + vsa[1]) + (vsa[2] + vsa[3]);
    // cross-quad reduce (px,py chains interleave; 2-deep DS latency)
    float px = vs.x, py = vs.y;
    px += __shfl_xor(px, 16); py += __shfl_xor(py, 16);
    px += __shfl_xor(px, 32); py += __shfl_xor(py, 32);
    return f32x2{px, py} + b3v;
  };

  #pragma unroll 1
  for (int iv = 0; iv < TT - 1; ++iv) {
    float t0 = tarr[iv], t1 = tarr[iv + 1];
    float dt = (t1 - t0) * 0.5f;
    #pragma unroll 1
    for (int ss = 0; ss < 2; ++ss) {
      float tb = (ss == 0) ? t0 : (t0 + dt);
      const f32x2 dtv = bc(dt);
      f32x2 k1 = feval(tb, S);
      f32x2 k2 = feval(tb + dt * F(1,5), pk_fma(bc(dt * F(1,5)), k1, S));
      f32x2 a3 = pk_fma(bc(F(9,40)), k2, bc(F(3,40)) * k1);
      f32x2 k3 = feval(tb + dt * F(3,10), pk_fma(dtv, a3, S));
      f32x2 a4 = pk_fma(bc(F(44,45)), k1,
                 pk_fma(bc(-F(56,15)), k2, bc(F(32,9)) * k3));
      f32x2 k4 = feval(tb + dt * F(4,5), pk_fma(dtv, a4, S));
      f32x2 a5 = pk_fma(bc(F(19372,6561)), k1,
                 pk_fma(bc(-F(25360,2187)), k2,
                 pk_fma(bc(F(64448,6561)), k3, bc(-F(212,729)) * k4)));
      f32x2 k5 = feval(tb + dt * F(8,9), pk_fma(dtv, a5, S));
      f32x2 a6 = pk_fma(bc(F(9017,3168)), k1,
                 pk_fma(bc(-F(355,33)), k2,
                 pk_fma(bc(F(46732,5247)), k3,
                 pk_fma(bc(F(49,176)), k4, bc(-F(5103,18656)) * k5))));
      f32x2 k6 = feval(tb + dt, pk_fma(dtv, a6, S));
      f32x2 fin = pk_fma(bc(F(35,384)), k1,
                  pk_fma(bc(F(500,1113)), k3,
                  pk_fma(bc(F(125,192)), k4,
                  pk_fma(bc(-F(2187,6784)), k5, bc(F(11,84)) * k6))));
      S = pk_fma(dtv, fin, S);
    }
    if (lane < 16) *(float2*)&out[(s * TT + iv + 1) * 2] = make_float2(S.x, S.y);
  }
}

extern "C" void kernel_launch(void* const* d_in, const int* in_sizes, int n_in,
                              void* d_out, int out_size, void* d_ws, size_t ws_size,
                              hipStream_t stream) {
  const float* r0 = (const float*)d_in[0];
  const float* t  = (const float*)d_in[1];
  const float* W1 = (const float*)d_in[2];
  const float* b1 = (const float*)d_in[3];
  const float* W2 = (const float*)d_in[4];
  const float* b2 = (const float*)d_in[5];
  const float* W3 = (const float*)d_in[6];
  const float* b3 = (const float*)d_in[7];
  float* out = (float*)d_out;
  const int B = in_sizes[0] / 2;        // 16384
  dim3 grid(B / 16), block(64);         // 1024 blocks x 64 threads (1 wave)
  node_kernel<<<grid, block, 0, stream>>>(r0, t, W1, b1, W2, b2, W3, b3, out);
}